// Round 4
// baseline (477.391 us; speedup 1.0000x reference)
//
#include <hip/hip_runtime.h>
#include <cstddef>

// CSWinBlock on MI355X — round 4: swapped-operand MFMA (n-contiguous outputs),
// weights direct from global (L2-resident), padded LDS tiles, no global_load_lds.
// ws layout (<= 97 MB):
//   [0, 32MB)    q-plane bf16 [NTOK][128]  (attention output in-place)
//   [32, 64MB)   k-plane, [64, 96MB) v-plane
//   [96MB, +384KB) bf16 weights

#define LDIM 16384
#define NTOK 131072
#define PLANE ((size_t)NTOK * 128)

typedef short bf16x8 __attribute__((ext_vector_type(8)));
typedef float f32x4 __attribute__((ext_vector_type(4)));

__device__ __forceinline__ unsigned short f2bf(float f) {   // RNE (weights only)
  union { float f; unsigned int i; } u; u.f = f;
  unsigned int r = u.i + 0x7fffu + ((u.i >> 16) & 1u);
  return (unsigned short)(r >> 16);
}
__device__ __forceinline__ unsigned int fb(float f) {
  union { float f; unsigned int i; } u; u.f = f; return u.i;
}
__device__ __forceinline__ float bflo(unsigned int u) {
  union { unsigned int i; float f; } x; x.i = u << 16; return x.f;
}
__device__ __forceinline__ float bfhi(unsigned int u) {
  union { unsigned int i; float f; } x; x.i = u & 0xffff0000u; return x.f;
}
// pack hi16(a) | hi16(b)<<16 — single v_perm_b32 (RTZ bf16)
__device__ __forceinline__ unsigned int pk2(float a, float b) {
  return __builtin_amdgcn_perm(fb(b), fb(a), 0x07060302u);
}
__device__ __forceinline__ unsigned short bft(float f) { return (unsigned short)(fb(f) >> 16); }

__device__ __forceinline__ float gelu_t(float x) {
  const float y = 1.5957691216057308f * (x + 0.044715f * x * x * x);
  const float e = __expf(y);
  return x * e / (e + 1.f);          // == 0.5x(1+tanh(y/2))
}

// ================= Kernel 0: weights fp32 -> bf16 (RNE, once) =================
__global__ void k_prep(const float* __restrict__ wq, const float* __restrict__ wp,
                       const float* __restrict__ w1, const float* __restrict__ w2,
                       unsigned short* __restrict__ wb)
{
  const int id = blockIdx.x * 256 + threadIdx.x;   // 49152 threads x 4 elems
  const float* src; int off;
  if (id < 12288)      { src = wq; off = id; }
  else if (id < 16384) { src = wp; off = id - 12288; }
  else if (id < 32768) { src = w1; off = id - 16384; }
  else                 { src = w2; off = id - 32768; }
  const float4 v = *(const float4*)(src + (size_t)off * 4);
  uint2 u;
  u.x = (unsigned)f2bf(v.x) | ((unsigned)f2bf(v.y) << 16);
  u.y = (unsigned)f2bf(v.z) | ((unsigned)f2bf(v.w) << 16);
  *(uint2*)(wb + (size_t)id * 4) = u;
}

// ================= Kernel 1: LN1 + QKV GEMM (1 barrier) =================
__global__ __launch_bounds__(256, 3) void k_ln_qkv(
    const float* __restrict__ x, const float* __restrict__ g, const float* __restrict__ bb,
    const unsigned short* __restrict__ wqkvb, unsigned short* __restrict__ qkv)
{
  __shared__ unsigned short xs[128 * 136];
  const int tid = threadIdx.x;
  const long m0 = (long)blockIdx.x * 128;
  { // LN: 2 threads/row, shfl pair-reduce
    const int m = tid >> 1, hf = tid & 1;
    const float4* xg = (const float4*)(x + (size_t)(m0 + m) * 128 + hf * 64);
    float4 xv[16];
    #pragma unroll
    for (int i = 0; i < 16; i++) xv[i] = xg[i];
    float s1 = 0.f, s2 = 0.f;
    #pragma unroll
    for (int i = 0; i < 16; i++) {
      s1 += xv[i].x + xv[i].y + xv[i].z + xv[i].w;
      s2 += xv[i].x * xv[i].x + xv[i].y * xv[i].y + xv[i].z * xv[i].z + xv[i].w * xv[i].w;
    }
    s1 += __shfl_xor(s1, 1); s2 += __shfl_xor(s2, 1);
    const float mean = s1 * (1.f / 128.f);
    const float var  = s2 * (1.f / 128.f) - mean * mean;
    const float rs = rsqrtf(var + 1e-5f);
    const float4* g4 = (const float4*)(g + hf * 64);
    const float4* b4 = (const float4*)(bb + hf * 64);
    #pragma unroll
    for (int i = 0; i < 8; i++) {
      float4 v0 = xv[2 * i], v1 = xv[2 * i + 1];
      float4 g0 = g4[2 * i], g1 = g4[2 * i + 1], p0 = b4[2 * i], p1 = b4[2 * i + 1];
      uint4 u;
      u.x = pk2((v0.x - mean) * rs * g0.x + p0.x, (v0.y - mean) * rs * g0.y + p0.y);
      u.y = pk2((v0.z - mean) * rs * g0.z + p0.z, (v0.w - mean) * rs * g0.w + p0.w);
      u.z = pk2((v1.x - mean) * rs * g1.x + p1.x, (v1.y - mean) * rs * g1.y + p1.y);
      u.w = pk2((v1.z - mean) * rs * g1.z + p1.z, (v1.w - mean) * rs * g1.w + p1.w);
      *(uint4*)&xs[m * 136 + (hf * 8 + i) * 8] = u;
    }
  }
  __syncthreads();
  const int lane = tid & 63, q = lane >> 4, r = lane & 15, wv = tid >> 6;
  #pragma unroll 1
  for (int nc = 0; nc < 3; nc++) {
    f32x4 acc[2][8];
    #pragma unroll
    for (int a = 0; a < 2; a++)
      #pragma unroll
      for (int b = 0; b < 8; b++) acc[a][b] = f32x4{0.f, 0.f, 0.f, 0.f};
    #pragma unroll
    for (int kc = 0; kc < 4; kc++) {
      bf16x8 a[2], b[8];
      #pragma unroll
      for (int nt = 0; nt < 2; nt++)
        a[nt] = *(const bf16x8*)(wqkvb + (size_t)(nc * 128 + wv * 32 + nt * 16 + r) * 128 + kc * 32 + q * 8);
      #pragma unroll
      for (int mt = 0; mt < 8; mt++)
        b[mt] = *(const bf16x8*)&xs[(mt * 16 + r) * 136 + kc * 32 + q * 8];
      #pragma unroll
      for (int nt = 0; nt < 2; nt++)
        #pragma unroll
        for (int mt = 0; mt < 8; mt++)
          acc[nt][mt] = __builtin_amdgcn_mfma_f32_16x16x32_bf16(a[nt], b[mt], acc[nt][mt], 0, 0, 0);
    }
    unsigned short* plane = qkv + (size_t)nc * PLANE;
    #pragma unroll
    for (int nt = 0; nt < 2; nt++)
      #pragma unroll
      for (int mt = 0; mt < 8; mt++) {
        const size_t tok = m0 + mt * 16 + r;
        const int col = wv * 32 + nt * 16 + q * 4;
        uint2 u;
        u.x = pk2(acc[nt][mt][0], acc[nt][mt][1]);
        u.y = pk2(acc[nt][mt][2], acc[nt][mt][3]);
        *(uint2*)(plane + tok * 128 + col) = u;
      }
  }
}

// ================= Kernel 2: CSWin attention (S^T MFMA flash) =================
__global__ __launch_bounds__(256, 2) void k_attn(
    const unsigned short* __restrict__ qkv, unsigned short* __restrict__ att)
{
  __shared__ unsigned short Kt[256][40];
  __shared__ unsigned short Vt[32][264];
  __shared__ unsigned short Ps[4][64][72];   // P^T per wave: [t][s(64)+pad]
  const unsigned short* kpl = qkv + PLANE;
  const unsigned short* vpl = qkv + 2 * PLANE;
  const int t = threadIdx.x;
  const int win = blockIdx.x, head = blockIdx.y, br = blockIdx.z;
  const int bimg = win >> 6, widx = win & 63;
  const int c0 = br * 64 + head * 32;
  const int lgWs = (br == 0) ? 1 : 7;
  const int Wsm1 = (1 << lgWs) - 1;
  const long base = (long)bimg * LDIM + ((br == 0) ? widx * 2 : widx * 256);

  { // stage K + V^T (thread t = key t)
    const long tj = base + (long)(t >> lgWs) * 128 + (t & Wsm1);
    const uint4* kp = (const uint4*)(kpl + (size_t)tj * 128 + c0);
    uint4 k0v = kp[0], k1v = kp[1], k2v = kp[2], k3v = kp[3];
    *(uint4*)&Kt[t][0]  = k0v;  *(uint4*)&Kt[t][8]  = k1v;
    *(uint4*)&Kt[t][16] = k2v;  *(uint4*)&Kt[t][24] = k3v;
    const uint4* vp = (const uint4*)(vpl + (size_t)tj * 128 + c0);
    uint4 vv[4] = {vp[0], vp[1], vp[2], vp[3]};
    const unsigned short* vs = (const unsigned short*)vv;
    #pragma unroll
    for (int d = 0; d < 32; d++) Vt[d][t] = vs[d];
  }
  const int wave = t >> 6, lane = t & 63, q = lane >> 4, r = lane & 15;
  const int qbase = wave * 64;
  bf16x8 qf[4];
  #pragma unroll
  for (int tc = 0; tc < 4; tc++) {
    const int row = qbase + tc * 16 + r;
    const long tok = base + (long)(row >> lgWs) * 128 + (row & Wsm1);
    qf[tc] = *(const bf16x8*)(qkv + (size_t)tok * 128 + c0 + q * 8);
  }
  __syncthreads();

  const float factor = 0.17677669529663687f * 1.44269504088896341f; // scale*log2e
  f32x4 Oacc[4][2];        // [tc][dc]: row=t=q*4+rg, col=d=r
  float psum[4];           // per tc, for t = tc*16 + r
  #pragma unroll
  for (int tc = 0; tc < 4; tc++) {
    Oacc[tc][0] = f32x4{0.f, 0.f, 0.f, 0.f};
    Oacc[tc][1] = f32x4{0.f, 0.f, 0.f, 0.f};
    psum[tc] = 0.f;
  }

  for (int kc = 0; kc < 4; kc++) {
    bf16x8 kb[4];
    #pragma unroll
    for (int sc = 0; sc < 4; sc++) kb[sc] = *(const bf16x8*)&Kt[kc * 64 + sc * 16 + r][q * 8];
    // S^T = mfma(K, Q): row = s = q*4+rg, col = t = r
    f32x4 s[4][4];
    #pragma unroll
    for (int sc = 0; sc < 4; sc++)
      #pragma unroll
      for (int tc = 0; tc < 4; tc++) {
        f32x4 z = f32x4{0.f, 0.f, 0.f, 0.f};
        s[sc][tc] = __builtin_amdgcn_mfma_f32_16x16x32_bf16(kb[sc], qf[tc], z, 0, 0, 0);
      }
    #pragma unroll
    for (int sc = 0; sc < 4; sc++)
      #pragma unroll
      for (int tc = 0; tc < 4; tc++) {
        const float p0 = exp2f(s[sc][tc][0] * factor);
        const float p1 = exp2f(s[sc][tc][1] * factor);
        const float p2 = exp2f(s[sc][tc][2] * factor);
        const float p3 = exp2f(s[sc][tc][3] * factor);
        psum[tc] += (p0 + p1) + (p2 + p3);
        uint2 u; u.x = pk2(p0, p1); u.y = pk2(p2, p3);
        *(uint2*)&Ps[wave][tc * 16 + r][sc * 16 + q * 4] = u;   // b64, conflict-free
      }
    // O += P V: A = P rows t, B = V^T rows d
    #pragma unroll
    for (int kst = 0; kst < 2; kst++) {
      bf16x8 pa[4], vb[2];
      #pragma unroll
      for (int tc = 0; tc < 4; tc++) pa[tc] = *(const bf16x8*)&Ps[wave][tc * 16 + r][kst * 32 + q * 8];
      #pragma unroll
      for (int dc = 0; dc < 2; dc++) vb[dc] = *(const bf16x8*)&Vt[dc * 16 + r][kc * 64 + kst * 32 + q * 8];
      #pragma unroll
      for (int tc = 0; tc < 4; tc++)
        #pragma unroll
        for (int dc = 0; dc < 2; dc++)
          Oacc[tc][dc] = __builtin_amdgcn_mfma_f32_16x16x32_bf16(pa[tc], vb[dc], Oacc[tc][dc], 0, 0, 0);
    }
  }

  float inv[4];
  #pragma unroll
  for (int tc = 0; tc < 4; tc++) {
    float v = psum[tc];
    v += __shfl_xor(v, 16); v += __shfl_xor(v, 32);   // reduce over quads
    inv[tc] = 1.f / v;                                 // valid for t = tc*16 + r
  }
  #pragma unroll
  for (int tc = 0; tc < 4; tc++)
    #pragma unroll
    for (int rg = 0; rg < 4; rg++) {
      const float nv = __shfl(inv[tc], q * 4 + rg);    // fetch psum for t = tc*16+q*4+rg
      const int row = qbase + tc * 16 + q * 4 + rg;
      const long tok = base + (long)(row >> lgWs) * 128 + (row & Wsm1);
      #pragma unroll
      for (int dc = 0; dc < 2; dc++)
        att[(size_t)tok * 128 + c0 + dc * 16 + r] = bft(Oacc[tc][dc][rg] * nv);
    }
}

// ================= Kernel 3: LePE depthwise 3x3, accumulate into att =================
__global__ __launch_bounds__(256, 2) void k_lepe(
    const unsigned short* __restrict__ qkv,
    const float* __restrict__ conv_w0, const float* __restrict__ conv_b0,
    const float* __restrict__ conv_w1, const float* __restrict__ conv_b1,
    unsigned short* __restrict__ att)
{
  const unsigned short* vpl = qkv + 2 * PLANE;
  const int tid = threadIdx.x;
  const int br = blockIdx.y;
  const long tok = (long)blockIdx.x * 16 + (tid >> 4);
  const int c0 = br * 64;
  const int c = (tid & 15) * 4;
  const int rr = (int)(tok & (LDIM - 1));
  const int row = rr >> 7, colim = rr & 127;
  int i, j, Hs, Ws;
  if (br == 0) { i = row; j = colim & 1; Hs = 128; Ws = 2; }
  else         { i = row & 1; j = colim; Hs = 2;  Ws = 128; }
  const float* cw = br ? conv_w1 : conv_w0;
  const float* cb = br ? conv_b1 : conv_b0;
  float w[4][9];
  #pragma unroll
  for (int cc = 0; cc < 4; cc++)
    #pragma unroll
    for (int tp = 0; tp < 9; tp++) w[cc][tp] = cw[(c + cc) * 9 + tp];
  float a0 = cb[c], a1 = cb[c + 1], a2 = cb[c + 2], a3 = cb[c + 3];
  #pragma unroll
  for (int di = -1; di <= 1; di++) {
    if ((unsigned)(i + di) >= (unsigned)Hs) continue;
    #pragma unroll
    for (int dj = -1; dj <= 1; dj++) {
      if ((unsigned)(j + dj) >= (unsigned)Ws) continue;
      const long tp_tok = tok + di * 128 + dj;
      uint2 u = *(const uint2*)(vpl + (size_t)tp_tok * 128 + c0 + c);
      const int tap = (di + 1) * 3 + (dj + 1);
      a0 = fmaf(bflo(u.x), w[0][tap], a0);
      a1 = fmaf(bfhi(u.x), w[1][tap], a1);
      a2 = fmaf(bflo(u.y), w[2][tap], a2);
      a3 = fmaf(bfhi(u.y), w[3][tap], a3);
    }
  }
  uint2 a = *(const uint2*)(att + (size_t)tok * 128 + c0 + c);
  uint2 o;
  o.x = pk2(bflo(a.x) + a0, bfhi(a.x) + a1);
  o.y = pk2(bflo(a.y) + a2, bfhi(a.y) + a3);
  *(uint2*)(att + (size_t)tok * 128 + c0 + c) = o;
}

// ================= Kernel 4: proj + residual (LDS-free, 0 barriers) =================
__global__ __launch_bounds__(256, 4) void k_proj(
    const unsigned short* __restrict__ att, const unsigned short* __restrict__ wprojb,
    const float* __restrict__ b_proj, const float* __restrict__ x,
    float* __restrict__ out)
{
  const int tid = threadIdx.x;
  const int lane = tid & 63, q = lane >> 4, r = lane & 15;
  const int wv = tid >> 6, wm = wv & 1, wn = wv >> 1;
  const long m0 = (long)blockIdx.x * 128 + wm * 64;
  f32x4 acc[4][4];    // [nt][mt]
  #pragma unroll
  for (int a = 0; a < 4; a++)
    #pragma unroll
    for (int b = 0; b < 4; b++) acc[a][b] = f32x4{0.f, 0.f, 0.f, 0.f};
  #pragma unroll
  for (int kc = 0; kc < 4; kc++) {
    bf16x8 a[4], b[4];
    #pragma unroll
    for (int nt = 0; nt < 4; nt++)
      a[nt] = *(const bf16x8*)(wprojb + (size_t)(wn * 64 + nt * 16 + r) * 128 + kc * 32 + q * 8);
    #pragma unroll
    for (int mt = 0; mt < 4; mt++)
      b[mt] = *(const bf16x8*)(att + (size_t)(m0 + mt * 16 + r) * 128 + kc * 32 + q * 8);
    #pragma unroll
    for (int nt = 0; nt < 4; nt++)
      #pragma unroll
      for (int mt = 0; mt < 4; mt++)
        acc[nt][mt] = __builtin_amdgcn_mfma_f32_16x16x32_bf16(a[nt], b[mt], acc[nt][mt], 0, 0, 0);
  }
  #pragma unroll
  for (int nt = 0; nt < 4; nt++)
    #pragma unroll
    for (int mt = 0; mt < 4; mt++) {
      const size_t tok = m0 + mt * 16 + r;
      const int col = wn * 64 + nt * 16 + q * 4;
      const float4 bv = *(const float4*)(b_proj + col);
      const float4 xr = *(const float4*)(x + tok * 128 + col);
      float4 o;
      o.x = xr.x + bv.x + acc[nt][mt][0];
      o.y = xr.y + bv.y + acc[nt][mt][1];
      o.z = xr.z + bv.z + acc[nt][mt][2];
      o.w = xr.w + bv.w + acc[nt][mt][3];
      *(float4*)(out + tok * 128 + col) = o;
    }
}

// ============ Kernel 5: fused LN2 + FFN1 + GELU + FFN2 + residual ============
__global__ __launch_bounds__(256, 3) void k_mlp(
    const float* __restrict__ xr, const float* __restrict__ g, const float* __restrict__ bb,
    const unsigned short* __restrict__ w1b, const unsigned short* __restrict__ w2b,
    const float* __restrict__ b1, const float* __restrict__ b2,
    float* __restrict__ out)
{
  __shared__ unsigned short xs[64 * 136];
  __shared__ unsigned short hs[64 * 136];
  const int tid = threadIdx.x;
  const long m0 = (long)blockIdx.x * 64;
  { // LN2: 4 threads/row
    const int m = tid >> 2, p = tid & 3;
    const float* xrow = xr + (size_t)(m0 + m) * 128 + p * 32;
    float4 xv[8];
    #pragma unroll
    for (int i = 0; i < 8; i++) xv[i] = ((const float4*)xrow)[i];
    float s1 = 0.f, s2 = 0.f;
    #pragma unroll
    for (int i = 0; i < 8; i++) {
      s1 += xv[i].x + xv[i].y + xv[i].z + xv[i].w;
      s2 += xv[i].x * xv[i].x + xv[i].y * xv[i].y + xv[i].z * xv[i].z + xv[i].w * xv[i].w;
    }
    s1 += __shfl_xor(s1, 1); s1 += __shfl_xor(s1, 2);
    s2 += __shfl_xor(s2, 1); s2 += __shfl_xor(s2, 2);
    const float mean = s1 * (1.f / 128.f);
    const float var  = s2 * (1.f / 128.f) - mean * mean;
    const float rs = rsqrtf(var + 1e-5f);
    const float4* g4 = (const float4*)(g + p * 32);
    const float4* b4 = (const float4*)(bb + p * 32);
    #pragma unroll
    for (int i = 0; i < 4; i++) {
      float4 v0 = xv[2 * i], v1 = xv[2 * i + 1];
      float4 g0 = g4[2 * i], g1 = g4[2 * i + 1], p0 = b4[2 * i], p1 = b4[2 * i + 1];
      uint4 u;
      u.x = pk2((v0.x - mean) * rs * g0.x + p0.x, (v0.y - mean) * rs * g0.y + p0.y);
      u.y = pk2((v0.z - mean) * rs * g0.z + p0.z, (v0.w - mean) * rs * g0.w + p0.w);
      u.z = pk2((v1.x - mean) * rs * g1.x + p1.x, (v1.y - mean) * rs * g1.y + p1.y);
      u.w = pk2((v1.z - mean) * rs * g1.z + p1.z, (v1.w - mean) * rs * g1.w + p1.w);
      *(uint4*)&xs[m * 136 + (p * 4 + i) * 8] = u;
    }
  }
  __syncthreads();
  const int lane = tid & 63, q = lane >> 4, r = lane & 15, wv = tid >> 6;
  f32x4 oacc[2][4];
  #pragma unroll
  for (int a = 0; a < 2; a++)
    #pragma unroll
    for (int b = 0; b < 4; b++) oacc[a][b] = f32x4{0.f, 0.f, 0.f, 0.f};

  #pragma unroll 1
  for (int nc = 0; nc < 4; nc++) {
    // GEMM1: h^T chunk = mfma(w1, xln): row = hidden n, col = token
    f32x4 h[2][4];
    #pragma unroll
    for (int a = 0; a < 2; a++)
      #pragma unroll
      for (int b = 0; b < 4; b++) h[a][b] = f32x4{0.f, 0.f, 0.f, 0.f};
    #pragma unroll
    for (int kc = 0; kc < 4; kc++) {
      bf16x8 a[2], b[4];
      #pragma unroll
      for (int nt = 0; nt < 2; nt++)
        a[nt] = *(const bf16x8*)(w1b + (size_t)(nc * 128 + wv * 32 + nt * 16 + r) * 128 + kc * 32 + q * 8);
      #pragma unroll
      for (int mt = 0; mt < 4; mt++)
        b[mt] = *(const bf16x8*)&xs[(mt * 16 + r) * 136 + kc * 32 + q * 8];
      #pragma unroll
      for (int nt = 0; nt < 2; nt++)
        #pragma unroll
        for (int mt = 0; mt < 4; mt++)
          h[nt][mt] = __builtin_amdgcn_mfma_f32_16x16x32_bf16(a[nt], b[mt], h[nt][mt], 0, 0, 0);
    }
    __syncthreads();    // prior GEMM2 reads of hs complete (overlapped with GEMM1)
    #pragma unroll
    for (int nt = 0; nt < 2; nt++)
      #pragma unroll
      for (int mt = 0; mt < 4; mt++) {
        const int col = wv * 32 + nt * 16 + q * 4;     // hidden n
        const float4 bv = *(const float4*)(b1 + nc * 128 + col);
        const float g0 = gelu_t(h[nt][mt][0] + bv.x);
        const float g1 = gelu_t(h[nt][mt][1] + bv.y);
        const float g2 = gelu_t(h[nt][mt][2] + bv.z);
        const float g3 = gelu_t(h[nt][mt][3] + bv.w);
        uint2 u; u.x = pk2(g0, g1); u.y = pk2(g2, g3);
        *(uint2*)&hs[(mt * 16 + r) * 136 + col] = u;   // b64, conflict-free
      }
    __syncthreads();    // hs ready
    // GEMM2 accumulate: out^T += mfma(w2, h)
    #pragma unroll
    for (int kc = 0; kc < 4; kc++) {
      bf16x8 a[2], b[4];
      #pragma unroll
      for (int nt = 0; nt < 2; nt++)
        a[nt] = *(const bf16x8*)(w2b + (size_t)(wv * 32 + nt * 16 + r) * 512 + nc * 128 + kc * 32 + q * 8);
      #pragma unroll
      for (int mt = 0; mt < 4; mt++)
        b[mt] = *(const bf16x8*)&hs[(mt * 16 + r) * 136 + kc * 32 + q * 8];
      #pragma unroll
      for (int nt = 0; nt < 2; nt++)
        #pragma unroll
        for (int mt = 0; mt < 4; mt++)
          oacc[nt][mt] = __builtin_amdgcn_mfma_f32_16x16x32_bf16(a[nt], b[mt], oacc[nt][mt], 0, 0, 0);
    }
  }
  #pragma unroll
  for (int nt = 0; nt < 2; nt++)
    #pragma unroll
    for (int mt = 0; mt < 4; mt++) {
      const size_t tok = m0 + mt * 16 + r;
      const int col = wv * 32 + nt * 16 + q * 4;
      const float4 bv = *(const float4*)(b2 + col);
      const float4 cur = *(const float4*)(out + tok * 128 + col);
      float4 o;
      o.x = cur.x + bv.x + oacc[nt][mt][0];
      o.y = cur.y + bv.y + oacc[nt][mt][1];
      o.z = cur.z + bv.z + oacc[nt][mt][2];
      o.w = cur.w + bv.w + oacc[nt][mt][3];
      *(float4*)(out + tok * 128 + col) = o;
    }
}

extern "C" void kernel_launch(void* const* d_in, const int* in_sizes, int n_in,
                              void* d_out, int out_size, void* d_ws, size_t ws_size,
                              hipStream_t stream) {
  const float* x       = (const float*)d_in[0];
  const float* ln1_g   = (const float*)d_in[1];
  const float* ln1_b   = (const float*)d_in[2];
  const float* w_qkv   = (const float*)d_in[3];
  const float* w_proj  = (const float*)d_in[4];
  const float* b_proj  = (const float*)d_in[5];
  const float* conv_w0 = (const float*)d_in[6];
  const float* conv_b0 = (const float*)d_in[7];
  const float* conv_w1 = (const float*)d_in[8];
  const float* conv_b1 = (const float*)d_in[9];
  const float* ln2_g   = (const float*)d_in[10];
  const float* ln2_b   = (const float*)d_in[11];
  const float* w1      = (const float*)d_in[12];
  const float* b1      = (const float*)d_in[13];
  const float* w2      = (const float*)d_in[14];
  const float* b2      = (const float*)d_in[15];
  float* out = (float*)d_out;

  unsigned short* qkv = (unsigned short*)d_ws;     // 3 planes [NTOK][128]
  unsigned short* att = qkv;                       // in-place in q-plane
  unsigned short* wb  = qkv + 3 * PLANE;
  unsigned short* wqkvb  = wb;
  unsigned short* wprojb = wb + 49152;
  unsigned short* w1b    = wb + 65536;
  unsigned short* w2b    = wb + 131072;

  k_prep<<<dim3(192), 256, 0, stream>>>(w_qkv, w_proj, w1, w2, wb);
  k_ln_qkv<<<dim3(NTOK / 128), 256, 0, stream>>>(x, ln1_g, ln1_b, wqkvb, qkv);
  k_attn<<<dim3(512, 2, 2), 256, 0, stream>>>(qkv, att);
  k_lepe<<<dim3(NTOK / 16, 2), 256, 0, stream>>>(qkv, conv_w0, conv_b0, conv_w1, conv_b1, att);
  k_proj<<<dim3(NTOK / 128), 256, 0, stream>>>(att, wprojb, b_proj, x, out);
  k_mlp<<<dim3(NTOK / 64), 256, 0, stream>>>(out, ln2_g, ln2_b, w1b, w2b, b1, b2, out);
}